// Round 9
// baseline (377.805 us; speedup 1.0000x reference)
//
#include <hip/hip_runtime.h>
#include <hip/hip_bf16.h>
#include <float.h>
#include <math.h>

#define HW 16384
#define NBATCH 4
#define DIM 256
#define NEGV (-1e30f)
#define NPP 160

// ---- workspace byte offsets ----
#define OFF_CHAN_SUM 0        // 256 f32
#define OFF_CHAN_SQ  1024
#define OFF_MEAN     2048
#define OFF_ISTD     3072
#define OFF_S1       4096     // 4*256 f32
#define OFF_S0       8192
#define OFF_CF       12288    // 4 int
#define OFF_CB       12304
#define OFF_BL       12320    // 8 f32
#define OFF_INCF     12352    // 8 f32 (ends 12384)
#define OFF_PPCNT    12416    // fast path: k_pp last-block counter (fallback: CCNT area)
#define OFF_QBUF     16384    // 8*256 f32 (ends 24576)
#define OFF_BCNT     24576    // 24*64 int segmented counts (ends 30720)
#define OFF_MCLS     40960    // 65536 int (0=none,1=fg,2=bg)
#define OFF_SELIDX   303104   // 8*160 int
#define OFF_SELW     308224   // 8*160 f32
#define OFF_ROWS     313344   // 8*160*256 f32 (ends 1,624,064)
#define OFF_W1T      1624064  // 256*256 f32 transposed w1 (ends 1,886,208)
#define OFF_RAW      1886208  // 65536*256 f32 cached raw proj (ends 68,995,072)
#define OFF_CKEYS_XL 68995072 // 24*16384 u64 (ends 72,140,800) — non-aliased
#define WS_NEED_FAST 68995072ull
#define WS_NEED_XL   72140800ull

#define NSEL 24
#define NTILE 1024            // matmul tiles; grid stays EXACTLY 1024 (=4 blk/CU x 256 CU
                              // residency) — 1048-block grid caused a 47us second wave (r8)

__device__ __forceinline__ unsigned f2mono(float f) {
  unsigned u = __float_as_uint(f);
  return (u & 0x80000000u) ? ~u : (u | 0x80000000u);
}

// bitonic sort of n (power of 2, <=128) u64 keys descending, payload si
__device__ __forceinline__ void sort_desc(unsigned long long* sk, int* si, int n, int tid) {
  for (int ksz = 2; ksz <= n; ksz <<= 1) {
    for (int j = ksz >> 1; j > 0; j >>= 1) {
      __syncthreads();
      if (tid < n) {
        int ixj = tid ^ j;
        if (ixj > tid) {
          unsigned long long a = sk[tid], b = sk[ixj];
          bool up = (tid & ksz) == 0;
          if (up ? (a < b) : (a > b)) {
            sk[tid] = b; sk[ixj] = a;
            int t2 = si[tid]; si[tid] = si[ixj]; si[ixj] = t2;
          }
        }
      }
    }
  }
  __syncthreads();
}

// ============ fast-path mask: no global atomics, segmented compaction ============
__global__ __launch_bounds__(256) void k_maskc2(
    const float* __restrict__ po, const float* __restrict__ pa,
    const float* __restrict__ unc, const int* __restrict__ lab,
    const float* __restrict__ r_anc, const float* __restrict__ r_pos,
    const float* __restrict__ r_neg, const float* __restrict__ w1,
    int* __restrict__ mcls, int* __restrict__ bcnt,
    unsigned long long* __restrict__ ckeys, float* __restrict__ w1T,
    float* __restrict__ chanSum, float* __restrict__ chanSq,
    float* __restrict__ S1, float* __restrict__ S0,
    int* __restrict__ ppcnt) {
  __shared__ int lcnt[24];
  int tid = threadIdx.x;
  int g = blockIdx.x * 256 + tid;                  // 0..65535
  int b = g >> 14;
  int lb = blockIdx.x & 63;                        // batch-local segment
  int i = g & (HW - 1);
  if (tid < 24) lcnt[tid] = 0;
  __syncthreads();
  float o0 = po[(size_t)(b*2+0)*HW + i];
  float o1 = po[(size_t)(b*2+1)*HW + i];
  float a0 = pa[(size_t)(b*2+0)*HW + i];
  float a1 = pa[(size_t)(b*2+1)*HW + i];
  bool rel = ((o1 > o0) == (a1 > a0));             // argmax tie -> idx0, strict >
  bool valid = rel && (unc[g] > 0.5f);
  int l = lab[g];
  int cls = valid ? ((l == 1) ? 1 : 2) : 0;
  mcls[g] = cls;
  int t0 = 0, t1 = 0, t2 = 0, loc0 = 0, loc1 = 0, loc2 = 0;
  unsigned long long k0 = 0, k1 = 0, k2 = 0;
  if (cls) {
    int co = cls - 1;                              // anchor class index
    unsigned idxf = (unsigned)(16383 - i);
    t0 = (b*2 + co)*3 + 0;
    t1 = (b*2 + co)*3 + 1;
    t2 = (b*2 + (1 - co))*3 + 2;
    k0 = ((unsigned long long)f2mono(r_anc[(size_t)(b*2 + co)*HW + i]) << 14) | idxf;
    k1 = ((unsigned long long)f2mono(r_pos[(size_t)(b*2 + co)*HW + i]) << 14) | idxf;
    k2 = ((unsigned long long)f2mono(r_neg[(size_t)(b*2 + (1 - co))*HW + i]) << 14) | idxf;
    loc0 = atomicAdd(&lcnt[t0], 1);
    loc1 = atomicAdd(&lcnt[t1], 1);
    loc2 = atomicAdd(&lcnt[t2], 1);
  }
  __syncthreads();
  if (tid < 24 && (tid / 6) == b)                  // this block owns segment lb of its batch's 6 tasks
    bcnt[tid*64 + lb] = lcnt[tid];
  if (cls) {
    ckeys[(size_t)t0*HW + lb*256 + loc0] = k0;
    ckeys[(size_t)t1*HW + lb*256 + loc1] = k1;
    ckeys[(size_t)t2*HW + lb*256 + loc2] = k2;
  }
  // ---- piggy-backed w1 transpose (blocks 0..15) ----
  if (blockIdx.x < 16) {
    int d0 = blockIdx.x * 16;
    float v[16];
    #pragma unroll
    for (int j = 0; j < 16; ++j) v[j] = w1[(size_t)tid*DIM + d0 + j];
    #pragma unroll
    for (int j = 0; j < 16; ++j) w1T[(size_t)(d0 + j)*DIM + tid] = v[j];
  }
  // ---- accumulator zeroing (consumed by later dispatches only) ----
  if (blockIdx.x == 16) { chanSum[tid] = 0.f; chanSq[tid] = 0.f; }
  if (blockIdx.x == 17) {
    #pragma unroll
    for (int j = 0; j < 4; ++j) S1[j*256 + tid] = 0.f;
  }
  if (blockIdx.x == 18) {
    #pragma unroll
    for (int j = 0; j < 4; ++j) S0[j*256 + tid] = 0.f;
  }
  if (blockIdx.x == 19 && tid == 0) *ppcnt = 0;
}

// ============ selection body over segmented keys (uses caller-provided LDS) ============
// sh layout: sk u64[128] @0 | si int[128] @1024 | cIdx int[128] @1536 |
//            hist int[256] @2048 | sufs int[256] @3072 | sbcnt int[64] @4096 |
//            cVal u8[128] @4352 | scal int[4] @4480  (total 4496 B)
__device__ void selc_body(const int* __restrict__ bcnt,
                          const unsigned long long* __restrict__ ckeys,
                          const float* __restrict__ unc,
                          int* __restrict__ selIdx, float* __restrict__ selW,
                          int* __restrict__ cf, int* __restrict__ cb,
                          int task, int tid, char* sh) {
  unsigned long long* sk = (unsigned long long*)sh;
  int* si    = (int*)(sh + 1024);
  int* cIdx  = (int*)(sh + 1536);
  int* hist  = (int*)(sh + 2048);
  int* sufs  = (int*)(sh + 3072);
  int* sbcnt = (int*)(sh + 4096);
  unsigned char* cVal = (unsigned char*)(sh + 4352);
  int* scal  = (int*)(sh + 4480);   // [0]=bin [1]=k [2]=gcnt [3]=cnt

  int pair = task / 3, which = task % 3;
  int b = pair >> 1, c = pair & 1;
  const unsigned long long* keys = ckeys + (size_t)task * HW;
  if (tid < 64) sbcnt[tid] = bcnt[task*64 + tid];
  __syncthreads();
  if (tid == 0) { int s = 0; for (int i2 = 0; i2 < 64; ++i2) s += sbcnt[i2]; scal[3] = s; }
  __syncthreads();
  int cnt = scal[3];
  if (which == 0 && tid == 0) { if (c == 0) cf[b] = cnt; else cb[b] = cnt; }
  int K1 = (which == 0) ? 32 : 128;
  int outBase = pair*NPP + (which == 0 ? 0 : (which == 1 ? 32 : 96));

  // ---- radix select: exact K1-th largest key ----
  unsigned long long pref = 0;
  if (cnt > K1) {
    const int shifts[6]  = {38, 30, 22, 14, 6, 0};
    const int bitsArr[6] = { 8,  8,  8,  8, 8, 6};
    int k = K1;
    for (int p = 0; p < 6; ++p) {
      int shift = shifts[p], nbits = bitsArr[p], nb = 1 << nbits;
      hist[tid] = 0;
      __syncthreads();
      for (int seg = 0; seg < 64; ++seg) {
        if (tid < sbcnt[seg]) {
          unsigned long long key = keys[seg*256 + tid];
          if ((key >> (shift + nbits)) == pref)
            atomicAdd(&hist[(int)((key >> shift) & (nb - 1))], 1);
        }
      }
      __syncthreads();
      if (tid < nb) sufs[tid] = hist[tid];
      __syncthreads();
      for (int off = 1; off < nb; off <<= 1) {
        int add = 0;
        if (tid < nb && tid + off < nb) add = sufs[tid + off];
        __syncthreads();
        if (tid < nb) sufs[tid] += add;
        __syncthreads();
      }
      if (tid < nb) {
        int sthis = sufs[tid];
        int snext = (tid + 1 < nb) ? sufs[tid + 1] : 0;
        if (sthis >= k && snext < k) { scal[0] = tid; scal[1] = k - snext; }
      }
      __syncthreads();
      pref = (pref << nbits) | (unsigned)scal[0];
      k = scal[1];
      __syncthreads();
    }
  }

  // ---- gather (keys unique -> exactly min(cnt,K1) survivors) ----
  if (tid == 0) scal[2] = 0;
  __syncthreads();
  for (int seg = 0; seg < 64; ++seg) {
    if (tid < sbcnt[seg]) {
      unsigned long long key = keys[seg*256 + tid];
      if (key >= pref) {
        int p2 = atomicAdd(&scal[2], 1);
        if (p2 < 128) { sk[p2] = key; si[p2] = 16383 - (int)(key & 16383); }
      }
    }
  }
  __syncthreads();
  int gcnt = scal[2];
  if (tid < K1 && tid >= gcnt) { sk[tid] = 0ull; si[tid] = 0; }  // weight-0 pads

  sort_desc(sk, si, K1, tid);

  if (which == 0) {
    if (tid < 32) {
      selIdx[outBase + tid] = si[tid];
      selW[outBase + tid]   = (sk[tid] != 0ull) ? 1.f : 0.f;
    }
    return;
  }

  // ---- stage 2: top-64 of 128 by (uncertainty desc, candidate pos asc) ----
  if (tid < 128) {
    cIdx[tid] = si[tid];
    cVal[tid] = (sk[tid] != 0ull) ? 1 : 0;
  }
  __syncthreads();
  if (tid < 128) {
    float u2 = cVal[tid] ? unc[(size_t)b*HW + cIdx[tid]] : NEGV;
    sk[tid] = ((unsigned long long)f2mono(u2) << 7) | (unsigned)(127 - tid);
    si[tid] = tid;
  }
  sort_desc(sk, si, 128, tid);
  if (tid < 64) {
    int t = si[tid];
    selIdx[outBase + tid] = cIdx[t];
    selW[outBase + tid]   = cVal[t] ? 1.f : 0.f;
  }
}

__global__ __launch_bounds__(256) void k_selc2(
    const int* __restrict__ bcnt, const unsigned long long* __restrict__ ckeys,
    const float* __restrict__ unc,
    int* __restrict__ selIdx, float* __restrict__ selW,
    int* __restrict__ cf, int* __restrict__ cb) {
  __shared__ __align__(16) char sh[4608];
  selc_body(bcnt, ckeys, unc, selIdx, selW, cf, cb, blockIdx.x, threadIdx.x, sh);
}

// ============ matmul body: EXACT round-3 structure (108 us, 72 VGPR, no spill) ============
// Do NOT register-pipeline (rounds 4/5 spilled both capped and uncapped).
#define BK 32
#define LDA 132

__device__ void mm8_body(
    const float* __restrict__ feat, const float* __restrict__ w1T,
    const int* __restrict__ mcls,
    float* __restrict__ chanSum, float* __restrict__ chanSq,
    float* __restrict__ rawout, int bid, int tid, float* smem) {
  float* As = smem;
  float* Bs = smem + BK*LDA;
  int ct = bid & 1;
  int rt = bid >> 1;
  int b  = rt >> 7;
  int i0 = (rt & 127) << 7;
  int c0 = ct << 7;
  int tx = tid & 15, ty = tid >> 4;
  float acc[8][8];
  #pragma unroll
  for (int r = 0; r < 8; ++r)
    #pragma unroll
    for (int c = 0; c < 8; ++c) acc[r][c] = 0.f;

  for (int kc = 0; kc < 8; ++kc) {
    int d0 = kc * BK;
    #pragma unroll
    for (int it = 0; it < 4; ++it) {
      int e = it*1024 + tid*4;
      int k = e >> 7, r = e & 127;
      float4 v = *(const float4*)&feat[((size_t)(b*DIM + d0 + k))*HW + i0 + r];
      *(float4*)&As[k*LDA + r] = v;
    }
    #pragma unroll
    for (int it = 0; it < 4; ++it) {
      int e = it*1024 + tid*4;
      int k = e >> 7, c = e & 127;
      float4 v = *(const float4*)&w1T[(size_t)(d0 + k)*DIM + c0 + c];
      *(float4*)&Bs[k*LDA + c] = v;
    }
    __syncthreads();
    #pragma unroll
    for (int k = 0; k < BK; ++k) {
      float4 a0 = *(const float4*)&As[k*LDA + ty*4];
      float4 a1 = *(const float4*)&As[k*LDA + 64 + ty*4];
      float4 b0 = *(const float4*)&Bs[k*LDA + tx*4];
      float4 b1 = *(const float4*)&Bs[k*LDA + 64 + tx*4];
      float ar[8] = {a0.x,a0.y,a0.z,a0.w, a1.x,a1.y,a1.z,a1.w};
      float bc[8] = {b0.x,b0.y,b0.z,b0.w, b1.x,b1.y,b1.z,b1.w};
      #pragma unroll
      for (int r = 0; r < 8; ++r)
        #pragma unroll
        for (int c = 0; c < 8; ++c)
          acc[r][c] += ar[r]*bc[c];
    }
    __syncthreads();
  }

  // ---- BN stats partials ----
  float* pS = smem;
  float* pQ = smem + 2048;
  #pragma unroll
  for (int c = 0; c < 8; ++c) {
    int lcol = (c < 4) ? (tx*4 + c) : (64 + tx*4 + (c - 4));
    float s = 0.f, q = 0.f;
    #pragma unroll
    for (int r = 0; r < 8; ++r) { float v = acc[r][c]; s += v; q += v*v; }
    pS[ty*128 + lcol] = s;
    pQ[ty*128 + lcol] = q;
  }
  __syncthreads();
  if (tid < 128) {
    float s = 0.f, q = 0.f;
    #pragma unroll
    for (int t2 = 0; t2 < 16; ++t2) { s += pS[t2*128 + tid]; q += pQ[t2*128 + tid]; }
    atomicAdd(&chanSum[c0 + tid], s);
    atomicAdd(&chanSq[c0 + tid],  q);
  }

  // ---- store raw rows for valid pixels ----
  #pragma unroll
  for (int r = 0; r < 8; ++r) {
    int lrow = (r < 4) ? (ty*4 + r) : (64 + ty*4 + (r - 4));
    int g = rt*128 + lrow;
    if (mcls[g] != 0) {
      float4 lo; lo.x = acc[r][0]; lo.y = acc[r][1]; lo.z = acc[r][2]; lo.w = acc[r][3];
      float4 hi; hi.x = acc[r][4]; hi.y = acc[r][5]; hi.z = acc[r][6]; hi.w = acc[r][7];
      *(float4*)&rawout[(size_t)g*DIM + c0 + tx*4]      = lo;
      *(float4*)&rawout[(size_t)g*DIM + c0 + 64 + tx*4] = hi;
    }
  }
}

// merged matmul + selection, grid EXACTLY NTILE blocks (one residency wave).
// Blocks 0..nSel-1 run selection THEN also compute the last nSel matmul tiles,
// so no block overflows the 4-blk/CU residency (r8's 1048-block grid forced a
// 24-block second wave: 108+47=155us). Both bodies share one LDS buffer.
__global__ __launch_bounds__(256) void k_mmsel(
    const float* __restrict__ feat, const float* __restrict__ w1T,
    const int* __restrict__ mcls,
    float* __restrict__ chanSum, float* __restrict__ chanSq,
    float* __restrict__ rawout,
    const int* __restrict__ bcnt, const unsigned long long* __restrict__ ckeys,
    const float* __restrict__ unc,
    int* __restrict__ selIdx, float* __restrict__ selW,
    int* __restrict__ cf, int* __restrict__ cb, int nSel) {
  __shared__ __align__(16) float smem[2*BK*LDA];
  int bid = blockIdx.x;
  if (bid < nSel) {
    selc_body(bcnt, ckeys, unc, selIdx, selW, cf, cb, bid, threadIdx.x, (char*)smem);
    __syncthreads();   // LDS reuse: selection reads done before matmul overwrites
    mm8_body(feat, w1T, mcls, chanSum, chanSq, rawout,
             NTILE - nSel + bid, threadIdx.x, smem);
  } else {
    mm8_body(feat, w1T, mcls, chanSum, chanSq, rawout, bid - nSel, threadIdx.x, smem);
  }
}

// ============ fused post-matmul: bnsum (blocks 0..255) + rowproj x4 (256..575) ============
__global__ __launch_bounds__(256) void k_post(
    const float* __restrict__ raw, const int* __restrict__ mcls,
    const float* __restrict__ chanSum, const float* __restrict__ chanSq,
    const float* __restrict__ gamma, const float* __restrict__ beta,
    const float* __restrict__ w2, const float* __restrict__ b2,
    const int* __restrict__ selIdx, const float* __restrict__ selW,
    float* __restrict__ S1, float* __restrict__ S0,
    float* __restrict__ rows) {
  __shared__ __align__(16) float sh[2048];
  const float nconst = (float)(NBATCH * HW);
  int tid = threadIdx.x;

  if (blockIdx.x < 256) {
    float* p1 = sh;
    float* p2 = sh + 1024;
    int w = tid >> 6, lane = tid & 63;
    int p0 = blockIdx.x << 8;
    int b = p0 >> 14;
    int ch = lane*4;
    float4 G = *(const float4*)&gamma[ch];
    float4 Bt = *(const float4*)&beta[ch];
    float4 CS = *(const float4*)&chanSum[ch];
    float4 CQ = *(const float4*)&chanSq[ch];
    float m0 = CS.x/nconst, m1 = CS.y/nconst, m2 = CS.z/nconst, m3 = CS.w/nconst;
    float v0 = CQ.x/nconst - m0*m0, v1 = CQ.y/nconst - m1*m1;
    float v2 = CQ.z/nconst - m2*m2, v3 = CQ.w/nconst - m3*m3;
    float i0 = 1.0f/sqrtf(v0 + 1e-5f), i1 = 1.0f/sqrtf(v1 + 1e-5f);
    float i2 = 1.0f/sqrtf(v2 + 1e-5f), i3 = 1.0f/sqrtf(v3 + 1e-5f);
    float A0 = G.x*i0, A1 = G.y*i1, A2 = G.z*i2, A3 = G.w*i3;
    float s1[4] = {0,0,0,0}, s0[4] = {0,0,0,0};
    int g0 = p0 + w*64;
    for (int t = 0; t < 64; ++t) {
      int g = g0 + t;
      int cls = mcls[g];
      if (cls == 0) continue;
      float4 v = *(const float4*)&raw[(size_t)g*DIM + ch];
      float r0 = A0*(v.x - m0) + Bt.x; r0 = r0 > 0.f ? r0 : 0.f;
      float r1 = A1*(v.y - m1) + Bt.y; r1 = r1 > 0.f ? r1 : 0.f;
      float r2 = A2*(v.z - m2) + Bt.z; r2 = r2 > 0.f ? r2 : 0.f;
      float r3 = A3*(v.w - m3) + Bt.w; r3 = r3 > 0.f ? r3 : 0.f;
      if (cls == 1) { s1[0]+=r0; s1[1]+=r1; s1[2]+=r2; s1[3]+=r3; }
      else          { s0[0]+=r0; s0[1]+=r1; s0[2]+=r2; s0[3]+=r3; }
    }
    #pragma unroll
    for (int j = 0; j < 4; ++j) {
      p1[w*256 + ch + j] = s1[j];
      p2[w*256 + ch + j] = s0[j];
    }
    __syncthreads();
    float a = p1[tid] + p1[256+tid] + p1[512+tid] + p1[768+tid];
    float d = p2[tid] + p2[256+tid] + p2[512+tid] + p2[768+tid];
    atomicAdd(&S1[b*DIM + tid], a);
    atomicAdd(&S0[b*DIM + tid], d);
  } else {
    float* rl  = sh;
    float* red = sh + 1024;
    int blk = blockIdx.x - 256;
    int slot0 = blk * 4;
    int pair = slot0 / NPP;
    int b = pair >> 1;
    int e = tid;
    float m = chanSum[e] / nconst;
    float v = chanSq[e] / nconst - m*m;
    float istd = 1.0f / sqrtf(v + 1e-5f);
    float A = gamma[e]*istd;
    float Bt = beta[e];
    bool ok[4];
    #pragma unroll
    for (int s = 0; s < 4; ++s) {
      int slot = slot0 + s;
      ok[s] = (selW[slot] != 0.f);
      float rv = 0.f;
      if (ok[s]) {
        int i = selIdx[slot];
        float acc = raw[((size_t)b*HW + i)*DIM + e];
        float bn = A*(acc - m) + Bt;
        rv = bn > 0.f ? bn : 0.f;
      }
      rl[s*256 + e] = rv;
    }
    __syncthreads();
    float b2e = b2[e];
    float pj[4] = {b2e, b2e, b2e, b2e};
    const float4* w4 = (const float4*)&w2[(size_t)e*DIM];
    #pragma unroll 8
    for (int d4 = 0; d4 < DIM/4; ++d4) {
      float4 w = w4[d4];
      #pragma unroll
      for (int s = 0; s < 4; ++s) {
        float4 a = *(const float4*)&rl[s*256 + d4*4];
        pj[s] += a.x*w.x + a.y*w.y + a.z*w.z + a.w*w.w;
      }
    }
    #pragma unroll
    for (int s = 0; s < 4; ++s) red[s*256 + e] = pj[s]*pj[s];
    __syncthreads();
    for (int off = 128; off > 0; off >>= 1) {
      if (e < off) {
        #pragma unroll
        for (int s = 0; s < 4; ++s) red[s*256 + e] += red[s*256 + e + off];
      }
      __syncthreads();
    }
    #pragma unroll
    for (int s = 0; s < 4; ++s) {
      float sc = 1.f / fmaxf(sqrtf(red[s*256]), 1e-12f);
      rows[(size_t)(slot0 + s)*DIM + e] = ok[s] ? pj[s]*sc : 0.f;
    }
  }
}

// ============ pair-loss body ============
__device__ void pair_body(
    const float* __restrict__ rows, const float* __restrict__ selW,
    const int* __restrict__ cf, const int* __restrict__ cb,
    float* __restrict__ BL, float* __restrict__ INCF, int pair, int tid) {
  __shared__ float q[32*257];
  __shared__ float pacc[256], nacc[256];
  __shared__ float red[64];
  int b = pair >> 1, c = pair & 1;
  for (int l = tid; l < 32*DIM; l += 256) {
    int r = l >> 8, d = l & 255;
    q[r*257 + d] = rows[((size_t)pair*NPP + r)*DIM + d];
  }
  __syncthreads();
  int g = tid >> 5, r = tid & 31;
  float ap = 0.f, an = 0.f;
  for (int so = 0; so < 8; ++so) {
    int s = so*8 + g;
    const float* Pr = &rows[((size_t)pair*NPP + 32 + s)*DIM];
    const float* Nr = &rows[((size_t)pair*NPP + 96 + s)*DIM];
    float dp = 0.f, dn = 0.f;
    for (int d = 0; d < DIM; ++d) {
      float qv = q[r*257 + d];
      dp += Pr[d]*qv;
      dn += Nr[d]*qv;
    }
    ap += expf(dp*10.f) * selW[pair*NPP + 32 + s];
    an += expf(dn*10.f) * selW[pair*NPP + 96 + s];
  }
  pacc[tid] = ap; nacc[tid] = an;
  __syncthreads();
  if (tid < 32) {
    float p = 0.f, n = 0.f;
    for (int gg = 0; gg < 8; ++gg) { p += pacc[gg*32 + tid]; n += nacc[gg*32 + tid]; }
    int amC = (c == 0) ? cf[b] : cb[b];
    int nmC = (c == 0) ? cb[b] : cf[b];
    bool inc = (amC >= 1) && (nmC >= 1);
    if (!inc) p += 1.f;
    float per = -logf(p / (p + n + 1e-8f));
    float af = selW[pair*NPP + tid];
    red[tid]      = per*af;
    red[32 + tid] = af;
  }
  __syncthreads();
  if (tid == 0) {
    float s = 0.f, sa = 0.f;
    for (int rr = 0; rr < 32; ++rr) { s += red[rr]; sa += red[32+rr]; }
    int amC = (c == 0) ? cf[b] : cb[b];
    int nmC = (c == 0) ? cb[b] : cf[b];
    bool inc = (amC >= 1) && (nmC >= 1);
    float bl = s / fmaxf(sa, 1.f);
    BL[pair]   = inc ? bl : 0.f;
    INCF[pair] = inc ? 1.f : 0.f;
  }
}

// ============ prototype body (64 threads) ============
__device__ void proto_body(
    const float* __restrict__ S1, const float* __restrict__ S0,
    const int* __restrict__ cf, const int* __restrict__ cb,
    const float* __restrict__ w2, const float* __restrict__ b2,
    float* __restrict__ qbuf, int idx, int l) {
  int b = idx >> 1, side = idx & 1;
  const float* S = (side == 0) ? &S1[b*DIM] : &S0[b*DIM];
  float cnt = (float)((side == 0) ? cf[b] : cb[b]);
  float m[4]; float n2p = 0.f;
  #pragma unroll
  for (int k = 0; k < 4; ++k) {
    int e = l + 64*k;
    float acc = 0.f;
    const float* w2r = &w2[(size_t)e*DIM];
    for (int d = 0; d < DIM; ++d) acc += S[d]*w2r[d];
    float mv = (acc + cnt*b2[e]) / fmaxf(cnt, 1.f);
    m[k] = mv; n2p += mv*mv;
  }
  #pragma unroll
  for (int off = 32; off > 0; off >>= 1) n2p += __shfl_down(n2p, off, 64);
  float n2 = __shfl(n2p, 0, 64);
  float sc = 1.f / fmaxf(sqrtf(n2), 1e-12f);
  #pragma unroll
  for (int k = 0; k < 4; ++k)
    qbuf[(size_t)(side*4 + b)*DIM + l + 64*k] = m[k]*sc;
}

// ============ global-loss body (one wave) ============
__device__ void glob_body(
    const float* __restrict__ qbuf,
    const int* __restrict__ cf, const int* __restrict__ cb,
    const float* __restrict__ BL, const float* __restrict__ INCF,
    float* __restrict__ out, int l) {
  float qf[4][4], qb[4][4];
  #pragma unroll
  for (int b = 0; b < 4; ++b)
    #pragma unroll
    for (int k = 0; k < 4; ++k) {
      qf[b][k] = qbuf[(size_t)b*DIM + l + 64*k];
      qb[b][k] = qbuf[(size_t)(4 + b)*DIM + l + 64*k];
    }
  float pd[24];
  #pragma unroll
  for (int j = 0; j < 4; ++j)
    #pragma unroll
    for (int b = 0; b < 4; ++b) {
      float s = 0.f;
      #pragma unroll
      for (int k = 0; k < 4; ++k) s += qb[j][k]*qf[b][k];
      pd[j*4 + b] = s;
    }
  #pragma unroll
  for (int b = 0; b < 4; ++b) {
    float s1 = 0.f, s2 = 0.f;
    #pragma unroll
    for (int k = 0; k < 4; ++k) { s1 += qf[b][k]*qf[b][k]; s2 += qb[b][k]*qb[b][k]; }
    pd[16 + b] = s1; pd[20 + b] = s2;
  }
  #pragma unroll
  for (int t = 0; t < 24; ++t)
    #pragma unroll
    for (int off = 32; off > 0; off >>= 1)
      pd[t] += __shfl_down(pd[t], off, 64);
  if (l == 0) {
    bool vg[4]; float vgs = 0.f;
    for (int b = 0; b < 4; ++b) {
      vg[b] = (cf[b] >= 1) && (cb[b] >= 1);
      if (vg[b]) vgs += 1.f;
    }
    float gsum = 0.f;
    for (int b = 0; b < 4; ++b) {
      float nf = 0.f, nb = 0.f;
      for (int j = 0; j <= b; ++j) if (vg[j]) {
        nf += expf(10.f*pd[j*4 + b]);
        nb += expf(10.f*pd[b*4 + j]);
      }
      float pf = expf(10.f*pd[16 + b]);
      float pb = expf(10.f*pd[20 + b]);
      float lg = -logf(pf/(pf + nf + 1e-8f)) - logf(pb/(pb + nb + 1e-8f));
      if (vg[b]) gsum += lg;
    }
    float l_global = gsum / fmaxf(vgs, 1.f);
    float bls = 0.f, incs = 0.f;
    for (int p = 0; p < 8; ++p) { bls += BL[p]; incs += INCF[p]; }
    float l_local = bls / fmaxf(incs, 1.f);
    out[0] = l_local + 0.5f*l_global;
    out[1] = l_local;
    out[2] = l_global;
  }
}

// merged pair (blocks 0..7) + proto (blocks 8..15) + last-block global loss.
__global__ __launch_bounds__(256) void k_pp(
    const float* __restrict__ rows, const float* __restrict__ selW,
    const int* __restrict__ cf, const int* __restrict__ cb,
    float* __restrict__ BL, float* __restrict__ INCF,
    const float* __restrict__ S1, const float* __restrict__ S0,
    const float* __restrict__ w2, const float* __restrict__ b2,
    float* __restrict__ qbuf, int* __restrict__ ppcnt,
    float* __restrict__ out) {
  __shared__ int isLast;
  if (blockIdx.x < 8) {
    pair_body(rows, selW, cf, cb, BL, INCF, blockIdx.x, threadIdx.x);
  } else {
    if (threadIdx.x < 64)
      proto_body(S1, S0, cf, cb, w2, b2, qbuf, blockIdx.x - 8, threadIdx.x);
  }
  __syncthreads();
  __threadfence();                     // make this block's writes device-visible
  if (threadIdx.x == 0) isLast = (atomicAdd(ppcnt, 1) == 15);
  __syncthreads();
  if (isLast) {
    __threadfence();                   // acquire side
    if (threadIdx.x < 64)
      glob_body(qbuf, cf, cb, BL, INCF, out, threadIdx.x);
  }
}

// ================== fallback path (small workspace) ==================
__global__ void k_mask(const float* __restrict__ po, const float* __restrict__ pa,
                       const float* __restrict__ unc, const int* __restrict__ lab,
                       int* __restrict__ mcls, int* __restrict__ cf, int* __restrict__ cb) {
  int g = blockIdx.x * 256 + threadIdx.x;
  int b = g >> 14;
  int i = g & (HW - 1);
  float o0 = po[(size_t)(b*2+0)*HW + i];
  float o1 = po[(size_t)(b*2+1)*HW + i];
  float a0 = pa[(size_t)(b*2+0)*HW + i];
  float a1 = pa[(size_t)(b*2+1)*HW + i];
  bool rel = ((o1 > o0) == (a1 > a0));
  bool valid = rel && (unc[g] > 0.5f);
  int l = lab[g];
  int cls = valid ? ((l == 1) ? 1 : 2) : 0;
  mcls[g] = cls;
  if (cls == 1) atomicAdd(&cf[b], 1);
  if (cls == 2) atomicAdd(&cb[b], 1);
}

template<int MODE>
__global__ __launch_bounds__(256) void k_matmul(
    const float* __restrict__ feat, const float* __restrict__ w1,
    float* __restrict__ chanSum, float* __restrict__ chanSq,
    const float* __restrict__ meanr, const float* __restrict__ istd,
    const float* __restrict__ gamma, const float* __restrict__ beta,
    const int* __restrict__ mcls,
    float* __restrict__ S1, float* __restrict__ S0) {
  __shared__ __align__(16) float As[64*68];
  __shared__ __align__(16) float Bs[64*68];
  __shared__ float cA[64], cB[64];
  int tid = threadIdx.x;
  int rt = blockIdx.x;
  int ct = blockIdx.y;
  int b  = rt >> 8;
  int i0 = (rt & 255) << 6;
  int c0 = ct << 6;
  int tx = tid & 15, ty = tid >> 4;
  float acc[4][4] = {{0.f,0.f,0.f,0.f},{0.f,0.f,0.f,0.f},{0.f,0.f,0.f,0.f},{0.f,0.f,0.f,0.f}};
  for (int kc = 0; kc < 4; ++kc) {
    int d0 = kc << 6;
    #pragma unroll
    for (int it = 0; it < 4; ++it) {
      int k  = it*16 + (tid >> 4);
      int rq = tid & 15;
      float4 v = *(const float4*)&feat[((size_t)(b*DIM + d0 + k))*HW + i0 + rq*4];
      *(float4*)&As[k*68 + rq*4] = v;
    }
    #pragma unroll
    for (int it = 0; it < 4; ++it) {
      int col = it*16 + (tid >> 4);
      int kq  = tid & 15;
      float4 v = *(const float4*)&w1[(size_t)(c0 + col)*DIM + d0 + kq*4];
      Bs[(kq*4+0)*68 + col] = v.x;
      Bs[(kq*4+1)*68 + col] = v.y;
      Bs[(kq*4+2)*68 + col] = v.z;
      Bs[(kq*4+3)*68 + col] = v.w;
    }
    __syncthreads();
    #pragma unroll
    for (int k = 0; k < 64; ++k) {
      float4 av = *(const float4*)&As[k*68 + ty*4];
      float4 bv = *(const float4*)&Bs[k*68 + tx*4];
      float aa[4] = {av.x, av.y, av.z, av.w};
      float bb[4] = {bv.x, bv.y, bv.z, bv.w};
      #pragma unroll
      for (int rr = 0; rr < 4; ++rr)
        #pragma unroll
        for (int cc = 0; cc < 4; ++cc)
          acc[rr][cc] += aa[rr]*bb[cc];
    }
    __syncthreads();
  }
  if (tid < 64) { cA[tid] = 0.f; cB[tid] = 0.f; }
  __syncthreads();
  if (MODE == 0) {
    float s[4] = {0,0,0,0}, q[4] = {0,0,0,0};
    #pragma unroll
    for (int rr = 0; rr < 4; ++rr)
      #pragma unroll
      for (int cc = 0; cc < 4; ++cc) { float v = acc[rr][cc]; s[cc] += v; q[cc] += v*v; }
    #pragma unroll
    for (int cc = 0; cc < 4; ++cc) {
      atomicAdd(&cA[tx*4+cc], s[cc]);
      atomicAdd(&cB[tx*4+cc], q[cc]);
    }
    __syncthreads();
    if (tid < 64) {
      atomicAdd(&chanSum[c0 + tid], cA[tid]);
      atomicAdd(&chanSq[c0 + tid],  cB[tid]);
    }
  } else {
    float A[4], M[4], Bt[4];
    #pragma unroll
    for (int cc = 0; cc < 4; ++cc) {
      int c = c0 + tx*4 + cc;
      A[cc] = gamma[c]*istd[c]; M[cc] = meanr[c]; Bt[cc] = beta[c];
    }
    float s1[4] = {0,0,0,0}, s0[4] = {0,0,0,0};
    #pragma unroll
    for (int rr = 0; rr < 4; ++rr) {
      int g = rt*64 + ty*4 + rr;
      int cls = mcls[g];
      if (cls == 0) continue;
      #pragma unroll
      for (int cc = 0; cc < 4; ++cc) {
        float v = A[cc]*(acc[rr][cc] - M[cc]) + Bt[cc];
        v = v > 0.f ? v : 0.f;
        if (cls == 1) s1[cc] += v; else s0[cc] += v;
      }
    }
    #pragma unroll
    for (int cc = 0; cc < 4; ++cc) {
      atomicAdd(&cA[tx*4+cc], s1[cc]);
      atomicAdd(&cB[tx*4+cc], s0[cc]);
    }
    __syncthreads();
    if (tid < 64) {
      atomicAdd(&S1[b*DIM + c0 + tid], cA[tid]);
      atomicAdd(&S0[b*DIM + c0 + tid], cB[tid]);
    }
  }
}

__global__ void k_stats(const float* __restrict__ chanSum, const float* __restrict__ chanSq,
                        float* __restrict__ meanr, float* __restrict__ istd) {
  int e = threadIdx.x;
  const float n = (float)(NBATCH * HW);
  float m = chanSum[e] / n;
  float v = chanSq[e] / n - m*m;
  meanr[e] = m;
  istd[e]  = 1.0f / sqrtf(v + 1e-5f);
}

__global__ __launch_bounds__(256) void k_select(
    const int* __restrict__ mcls,
    const float* __restrict__ r_anc, const float* __restrict__ r_pos, const float* __restrict__ r_neg,
    const float* __restrict__ unc,
    int* __restrict__ selIdx, float* __restrict__ selW) {
  __shared__ int hist[256];
  __shared__ int sufs[256];
  __shared__ unsigned long long sk[128];
  __shared__ int si[128];
  __shared__ int cIdx[128];
  __shared__ unsigned char cVal[128];
  __shared__ int sh_bin, sh_k, gcnt;

  int tid  = threadIdx.x;
  int task = blockIdx.x;
  int pair = task / 3, which = task % 3;
  int b = pair >> 1, c = pair & 1;
  int wantA = (c == 0) ? 1 : 2;
  int want  = (which == 2) ? (3 - wantA) : wantA;
  const int* mc = mcls + (size_t)b * HW;
  const float* r = (which == 0) ? r_anc : (which == 1 ? r_pos : r_neg);
  r += (size_t)(b*2 + c) * HW;

  int K1 = (which == 0) ? 32 : 128;
  int outBase = pair*NPP + (which == 0 ? 0 : (which == 1 ? 32 : 96));

  const int shifts[6]  = {38, 30, 22, 14, 6, 0};
  const int bitsArr[6] = { 8,  8,  8,  8, 8, 6};
  unsigned long long pref = 0;
  int k = K1;
  for (int p = 0; p < 6; ++p) {
    int shift = shifts[p];
    int nbits = bitsArr[p];
    int nb = 1 << nbits;
    hist[tid] = 0;
    __syncthreads();
    int lastBin = -1, lc = 0;
    #pragma unroll 4
    for (int j = 0; j < 64; ++j) {
      int i = tid + j*256;
      float kv = (mc[i] == want) ? r[i] : NEGV;
      unsigned long long key = ((unsigned long long)f2mono(kv) << 14) | (unsigned)(16383 - i);
      if ((key >> (shift + nbits)) == pref) {
        int bin = (int)((key >> shift) & (nb - 1));
        if (bin == lastBin) { ++lc; }
        else {
          if (lastBin >= 0) atomicAdd(&hist[lastBin], lc);
          lastBin = bin; lc = 1;
        }
      }
    }
    if (lastBin >= 0) atomicAdd(&hist[lastBin], lc);
    __syncthreads();
    if (tid < nb) sufs[tid] = hist[tid];
    __syncthreads();
    for (int off = 1; off < nb; off <<= 1) {
      int add = 0;
      if (tid < nb && tid + off < nb) add = sufs[tid + off];
      __syncthreads();
      if (tid < nb) sufs[tid] += add;
      __syncthreads();
    }
    if (tid < nb) {
      int sthis = sufs[tid];
      int snext = (tid + 1 < nb) ? sufs[tid + 1] : 0;
      if (sthis >= k && snext < k) { sh_bin = tid; sh_k = k - snext; }
    }
    __syncthreads();
    pref = (pref << nbits) | (unsigned)sh_bin;
    k = sh_k;
    __syncthreads();
  }

  if (tid == 0) gcnt = 0;
  __syncthreads();
  #pragma unroll 4
  for (int j = 0; j < 64; ++j) {
    int i = tid + j*256;
    float kv = (mc[i] == want) ? r[i] : NEGV;
    unsigned long long key = ((unsigned long long)f2mono(kv) << 14) | (unsigned)(16383 - i);
    if (key >= pref) {
      int p2 = atomicAdd(&gcnt, 1);
      if (p2 < 128) { sk[p2] = key; si[p2] = i; }
    }
  }
  __syncthreads();
  if (tid < K1 && tid >= gcnt) { sk[tid] = 0ull; si[tid] = 0; }

  sort_desc(sk, si, K1, tid);

  if (which == 0) {
    if (tid < 32) {
      selIdx[outBase + tid] = si[tid];
      selW[outBase + tid]   = ((sk[tid] >> 14) >= 0x80000000ull) ? 1.f : 0.f;
    }
    return;
  }

  if (tid < 128) {
    cIdx[tid] = si[tid];
    cVal[tid] = ((sk[tid] >> 14) >= 0x80000000ull) ? 1 : 0;
  }
  __syncthreads();
  if (tid < 128) {
    float u2 = cVal[tid] ? unc[(size_t)b*HW + cIdx[tid]] : NEGV;
    sk[tid] = ((unsigned long long)f2mono(u2) << 7) | (unsigned)(127 - tid);
    si[tid] = tid;
  }
  sort_desc(sk, si, 128, tid);
  if (tid < 64) {
    int t = si[tid];
    selIdx[outBase + tid] = cIdx[t];
    selW[outBase + tid]   = cVal[t] ? 1.f : 0.f;
  }
}

__global__ __launch_bounds__(256) void k_rowproj(
    const float* __restrict__ feat, const float* __restrict__ w1, const float* __restrict__ w2,
    const float* __restrict__ b2, const float* __restrict__ gamma, const float* __restrict__ beta,
    const float* __restrict__ meanr, const float* __restrict__ istd,
    const int* __restrict__ selIdx, float* __restrict__ rows) {
  __shared__ __align__(16) float fr[DIM];
  __shared__ __align__(16) float rl[DIM];
  __shared__ float red[256];
  int slot = blockIdx.x;
  int pair = slot / NPP;
  int b = pair >> 1;
  int i = selIdx[slot];
  int e = threadIdx.x;
  fr[e] = feat[((size_t)(b*DIM + e))*HW + i];
  __syncthreads();
  float acc = 0.f;
  {
    const float4* f4 = (const float4*)fr;
    const float4* w4 = (const float4*)&w1[(size_t)e*DIM];
    #pragma unroll 8
    for (int d = 0; d < DIM/4; ++d) {
      float4 a = f4[d], w = w4[d];
      acc += a.x*w.x + a.y*w.y + a.z*w.z + a.w*w.w;
    }
  }
  float bn = gamma[e]*istd[e]*(acc - meanr[e]) + beta[e];
  rl[e] = bn > 0.f ? bn : 0.f;
  __syncthreads();
  float pj = b2[e];
  {
    const float4* f4 = (const float4*)rl;
    const float4* w4 = (const float4*)&w2[(size_t)e*DIM];
    #pragma unroll 8
    for (int d = 0; d < DIM/4; ++d) {
      float4 a = f4[d], w = w4[d];
      pj += a.x*w.x + a.y*w.y + a.z*w.z + a.w*w.w;
    }
  }
  red[e] = pj*pj;
  __syncthreads();
  for (int off = 128; off > 0; off >>= 1) {
    if (e < off) red[e] += red[e+off];
    __syncthreads();
  }
  float sc = 1.f / fmaxf(sqrtf(red[0]), 1e-12f);
  rows[(size_t)slot*DIM + e] = pj * sc;
}

__global__ __launch_bounds__(256) void k_pair(
    const float* __restrict__ rows, const float* __restrict__ selW,
    const int* __restrict__ cf, const int* __restrict__ cb,
    float* __restrict__ BL, float* __restrict__ INCF) {
  pair_body(rows, selW, cf, cb, BL, INCF, blockIdx.x, threadIdx.x);
}

__global__ __launch_bounds__(64) void k_proto(
    const float* __restrict__ S1, const float* __restrict__ S0,
    const int* __restrict__ cf, const int* __restrict__ cb,
    const float* __restrict__ w2, const float* __restrict__ b2,
    float* __restrict__ qbuf) {
  proto_body(S1, S0, cf, cb, w2, b2, qbuf, blockIdx.x, threadIdx.x);
}

__global__ __launch_bounds__(64) void k_glob(
    const float* __restrict__ qbuf,
    const int* __restrict__ cf, const int* __restrict__ cb,
    const float* __restrict__ BL, const float* __restrict__ INCF,
    float* __restrict__ out) {
  glob_body(qbuf, cf, cb, BL, INCF, out, threadIdx.x);
}

extern "C" void kernel_launch(void* const* d_in, const int* in_sizes, int n_in,
                              void* d_out, int out_size, void* d_ws, size_t ws_size,
                              hipStream_t stream) {
  const float* feat     = (const float*)d_in[0];
  const int*   labels   = (const int*)  d_in[1];
  const float* prob_ori = (const float*)d_in[2];
  const float* prob_aug = (const float*)d_in[3];
  const float* unc      = (const float*)d_in[4];
  const float* r_anc    = (const float*)d_in[5];
  const float* r_pos    = (const float*)d_in[6];
  const float* r_neg    = (const float*)d_in[7];
  const float* w1       = (const float*)d_in[8];
  // d_in[9] = b1: cancels inside BN (mean subtraction), unused
  const float* gamma    = (const float*)d_in[10];
  const float* beta     = (const float*)d_in[11];
  const float* w2       = (const float*)d_in[12];
  const float* b2       = (const float*)d_in[13];

  char* ws = (char*)d_ws;
  float* chanSum = (float*)(ws + OFF_CHAN_SUM);
  float* chanSq  = (float*)(ws + OFF_CHAN_SQ);
  float* meanr   = (float*)(ws + OFF_MEAN);
  float* istd    = (float*)(ws + OFF_ISTD);
  float* S1      = (float*)(ws + OFF_S1);
  float* S0      = (float*)(ws + OFF_S0);
  int*   cf      = (int*)  (ws + OFF_CF);
  int*   cb      = (int*)  (ws + OFF_CB);
  float* BLp     = (float*)(ws + OFF_BL);
  float* INCp    = (float*)(ws + OFF_INCF);
  int*   ppcnt   = (int*)  (ws + OFF_PPCNT);
  float* qbuf    = (float*)(ws + OFF_QBUF);
  int*   bcnt    = (int*)  (ws + OFF_BCNT);
  int*   mclsp   = (int*)  (ws + OFF_MCLS);
  int*   selIdx  = (int*)  (ws + OFF_SELIDX);
  float* selW    = (float*)(ws + OFF_SELW);
  float* rowsbuf = (float*)(ws + OFF_ROWS);
  float* w1T     = (float*)(ws + OFF_W1T);
  float* rawbuf  = (float*)(ws + OFF_RAW);

  if (ws_size >= WS_NEED_FAST) {
    bool xl = (ws_size >= WS_NEED_XL);
    unsigned long long* ckeys = (unsigned long long*)(ws + (xl ? OFF_CKEYS_XL : OFF_RAW));

    k_maskc2<<<256, 256, 0, stream>>>(prob_ori, prob_aug, unc, labels,
                                      r_anc, r_pos, r_neg, w1,
                                      mclsp, bcnt, ckeys, w1T,
                                      chanSum, chanSq, S1, S0, ppcnt);
    if (xl) {
      // grid EXACTLY NTILE: blocks 0..23 do selection then the last 24 tiles
      k_mmsel<<<NTILE, 256, 0, stream>>>(feat, w1T, mclsp, chanSum, chanSq, rawbuf,
                                         bcnt, ckeys, unc, selIdx, selW, cf, cb, NSEL);
    } else {
      // ckeys aliases RAW: selection must finish before matmul writes raw
      k_selc2<<<24, 256, 0, stream>>>(bcnt, ckeys, unc, selIdx, selW, cf, cb);
      k_mmsel<<<NTILE, 256, 0, stream>>>(feat, w1T, mclsp, chanSum, chanSq, rawbuf,
                                         bcnt, ckeys, unc, selIdx, selW, cf, cb, 0);
    }

    k_post<<<576, 256, 0, stream>>>(rawbuf, mclsp, chanSum, chanSq, gamma, beta,
                                    w2, b2, selIdx, selW, S1, S0, rowsbuf);

    k_pp<<<16, 256, 0, stream>>>(rowsbuf, selW, cf, cb, BLp, INCp,
                                 S1, S0, w2, b2, qbuf, ppcnt, (float*)d_out);
  } else {
    // fallback: two-pass tiled matmul + direct selection
    hipMemsetAsync(d_ws, 0, 16384, stream);
    k_mask<<<256, 256, 0, stream>>>(prob_ori, prob_aug, unc, labels, mclsp, cf, cb);
    dim3 gmm(1024, 4);
    k_matmul<0><<<gmm, 256, 0, stream>>>(feat, w1, chanSum, chanSq,
                                         meanr, istd, gamma, beta, mclsp, S1, S0);
    k_stats<<<1, 256, 0, stream>>>(chanSum, chanSq, meanr, istd);
    k_matmul<1><<<gmm, 256, 0, stream>>>(feat, w1, chanSum, chanSq,
                                         meanr, istd, gamma, beta, mclsp, S1, S0);
    k_select<<<24, 256, 0, stream>>>(mclsp, r_anc, r_pos, r_neg, unc, selIdx, selW);
    k_rowproj<<<1280, 256, 0, stream>>>(feat, w1, w2, b2, gamma, beta, meanr, istd,
                                        selIdx, rowsbuf);
    k_pair<<<8, 256, 0, stream>>>(rowsbuf, selW, cf, cb, BLp, INCp);
    k_proto<<<8, 64, 0, stream>>>(S1, S0, cf, cb, w2, b2, qbuf);
    k_glob<<<1, 64, 0, stream>>>(qbuf, cf, cb, BLp, INCp, (float*)d_out);
  }
}

// Round 10
// 298.329 us; speedup vs baseline: 1.2664x; 1.2664x over previous
//
#include <hip/hip_runtime.h>
#include <hip/hip_bf16.h>
#include <float.h>
#include <math.h>

#define HW 16384
#define NBATCH 4
#define DIM 256
#define NEGV (-1e30f)
#define NPP 160

// ---- workspace byte offsets ----
#define OFF_CHAN_SUM 0        // 256 f32
#define OFF_CHAN_SQ  1024
#define OFF_MEAN     2048
#define OFF_ISTD     3072
#define OFF_S1       4096     // 4*256 f32
#define OFF_S0       8192
#define OFF_CF       12288    // 4 int
#define OFF_CB       12304
#define OFF_BL       12320    // 8 f32
#define OFF_INCF     12352    // 8 f32 (ends 12384)
#define OFF_PPCNT    12416    // fast path: k_pp last-block counter
#define OFF_QBUF     16384    // 8*256 f32 (ends 24576)
#define OFF_BCNT     24576    // 24*64 int segmented counts (ends 30720)
#define OFF_MCLS     40960    // 65536 int (0=none,1=fg,2=bg)
#define OFF_SELIDX   303104   // 8*160 int
#define OFF_SELW     308224   // 8*160 f32
#define OFF_ROWS     313344   // 8*160*256 f32 (ends 1,624,064)
#define OFF_W1T      1624064  // 256*256 f32 transposed w1 (ends 1,886,208)
#define OFF_RAW      1886208  // 65536*256 f32 cached raw proj (ends 68,995,072)
#define OFF_CKEYS_XL 68995072 // 24*16384 u64 (ends 72,140,800) — non-aliased
#define WS_NEED_FAST 68995072ull
#define WS_NEED_XL   72140800ull

#define NSEL 24

__device__ __forceinline__ unsigned f2mono(float f) {
  unsigned u = __float_as_uint(f);
  return (u & 0x80000000u) ? ~u : (u | 0x80000000u);
}

// bitonic sort of n (power of 2, <=128) u64 keys descending, payload si
__device__ __forceinline__ void sort_desc(unsigned long long* sk, int* si, int n, int tid) {
  for (int ksz = 2; ksz <= n; ksz <<= 1) {
    for (int j = ksz >> 1; j > 0; j >>= 1) {
      __syncthreads();
      if (tid < n) {
        int ixj = tid ^ j;
        if (ixj > tid) {
          unsigned long long a = sk[tid], b = sk[ixj];
          bool up = (tid & ksz) == 0;
          if (up ? (a < b) : (a > b)) {
            sk[tid] = b; sk[ixj] = a;
            int t2 = si[tid]; si[tid] = si[ixj]; si[ixj] = t2;
          }
        }
      }
    }
  }
  __syncthreads();
}

// ============ fast-path mask: no global atomics, segmented compaction ============
__global__ __launch_bounds__(256) void k_maskc2(
    const float* __restrict__ po, const float* __restrict__ pa,
    const float* __restrict__ unc, const int* __restrict__ lab,
    const float* __restrict__ r_anc, const float* __restrict__ r_pos,
    const float* __restrict__ r_neg, const float* __restrict__ w1,
    int* __restrict__ mcls, int* __restrict__ bcnt,
    unsigned long long* __restrict__ ckeys, float* __restrict__ w1T,
    float* __restrict__ chanSum, float* __restrict__ chanSq,
    float* __restrict__ S1, float* __restrict__ S0,
    int* __restrict__ ppcnt) {
  __shared__ int lcnt[24];
  int tid = threadIdx.x;
  int g = blockIdx.x * 256 + tid;                  // 0..65535
  int b = g >> 14;
  int lb = blockIdx.x & 63;                        // batch-local segment
  int i = g & (HW - 1);
  if (tid < 24) lcnt[tid] = 0;
  __syncthreads();
  float o0 = po[(size_t)(b*2+0)*HW + i];
  float o1 = po[(size_t)(b*2+1)*HW + i];
  float a0 = pa[(size_t)(b*2+0)*HW + i];
  float a1 = pa[(size_t)(b*2+1)*HW + i];
  bool rel = ((o1 > o0) == (a1 > a0));             // argmax tie -> idx0, strict >
  bool valid = rel && (unc[g] > 0.5f);
  int l = lab[g];
  int cls = valid ? ((l == 1) ? 1 : 2) : 0;
  mcls[g] = cls;
  int t0 = 0, t1 = 0, t2 = 0, loc0 = 0, loc1 = 0, loc2 = 0;
  unsigned long long k0 = 0, k1 = 0, k2 = 0;
  if (cls) {
    int co = cls - 1;                              // anchor class index
    unsigned idxf = (unsigned)(16383 - i);
    t0 = (b*2 + co)*3 + 0;
    t1 = (b*2 + co)*3 + 1;
    t2 = (b*2 + (1 - co))*3 + 2;
    k0 = ((unsigned long long)f2mono(r_anc[(size_t)(b*2 + co)*HW + i]) << 14) | idxf;
    k1 = ((unsigned long long)f2mono(r_pos[(size_t)(b*2 + co)*HW + i]) << 14) | idxf;
    k2 = ((unsigned long long)f2mono(r_neg[(size_t)(b*2 + (1 - co))*HW + i]) << 14) | idxf;
    loc0 = atomicAdd(&lcnt[t0], 1);
    loc1 = atomicAdd(&lcnt[t1], 1);
    loc2 = atomicAdd(&lcnt[t2], 1);
  }
  __syncthreads();
  if (tid < 24 && (tid / 6) == b)                  // this block owns segment lb of its batch's 6 tasks
    bcnt[tid*64 + lb] = lcnt[tid];
  if (cls) {
    ckeys[(size_t)t0*HW + lb*256 + loc0] = k0;
    ckeys[(size_t)t1*HW + lb*256 + loc1] = k1;
    ckeys[(size_t)t2*HW + lb*256 + loc2] = k2;
  }
  // ---- piggy-backed w1 transpose (blocks 0..15) ----
  if (blockIdx.x < 16) {
    int d0 = blockIdx.x * 16;
    float v[16];
    #pragma unroll
    for (int j = 0; j < 16; ++j) v[j] = w1[(size_t)tid*DIM + d0 + j];
    #pragma unroll
    for (int j = 0; j < 16; ++j) w1T[(size_t)(d0 + j)*DIM + tid] = v[j];
  }
  // ---- accumulator zeroing (consumed by later dispatches only) ----
  if (blockIdx.x == 16) { chanSum[tid] = 0.f; chanSq[tid] = 0.f; }
  if (blockIdx.x == 17) {
    #pragma unroll
    for (int j = 0; j < 4; ++j) S1[j*256 + tid] = 0.f;
  }
  if (blockIdx.x == 18) {
    #pragma unroll
    for (int j = 0; j < 4; ++j) S0[j*256 + tid] = 0.f;
  }
  if (blockIdx.x == 19 && tid == 0) *ppcnt = 0;
}

// ============ selection body over segmented keys (uses caller-provided LDS) ============
// Segment-parallel: thread tid serves segment tid>>2, sub-lane tid&3 — all 64
// segments scanned concurrently (avg 8 iters) instead of 64 serial rounds.
// sh layout: sk u64[128] @0 | si int[128] @1024 | cIdx int[128] @1536 |
//            hist int[256] @2048 | sufs int[256] @3072 | sbcnt int[64] @4096 |
//            cVal u8[128] @4352 | scal int[4] @4480  (total 4496 B)
__device__ void selc_body(const int* __restrict__ bcnt,
                          const unsigned long long* __restrict__ ckeys,
                          const float* __restrict__ unc,
                          int* __restrict__ selIdx, float* __restrict__ selW,
                          int* __restrict__ cf, int* __restrict__ cb,
                          int task, int tid, char* sh) {
  unsigned long long* sk = (unsigned long long*)sh;
  int* si    = (int*)(sh + 1024);
  int* cIdx  = (int*)(sh + 1536);
  int* hist  = (int*)(sh + 2048);
  int* sufs  = (int*)(sh + 3072);
  int* sbcnt = (int*)(sh + 4096);
  unsigned char* cVal = (unsigned char*)(sh + 4352);
  int* scal  = (int*)(sh + 4480);   // [0]=bin [1]=k [2]=gcnt [3]=cnt

  int pair = task / 3, which = task % 3;
  int b = pair >> 1, c = pair & 1;
  const unsigned long long* keys = ckeys + (size_t)task * HW;
  if (tid < 64) sbcnt[tid] = bcnt[task*64 + tid];
  __syncthreads();
  if (tid == 0) { int s = 0; for (int i2 = 0; i2 < 64; ++i2) s += sbcnt[i2]; scal[3] = s; }
  __syncthreads();
  int cnt = scal[3];
  if (which == 0 && tid == 0) { if (c == 0) cf[b] = cnt; else cb[b] = cnt; }
  int K1 = (which == 0) ? 32 : 128;
  int outBase = pair*NPP + (which == 0 ? 0 : (which == 1 ? 32 : 96));

  int mseg = tid >> 2;              // segment served by this thread
  int msub = tid & 3;
  int mcnt = sbcnt[mseg];
  const unsigned long long* mkeys = keys + mseg*256;

  // ---- radix select: exact K1-th largest key ----
  unsigned long long pref = 0;
  if (cnt > K1) {
    const int shifts[6]  = {38, 30, 22, 14, 6, 0};
    const int bitsArr[6] = { 8,  8,  8,  8, 8, 6};
    int k = K1;
    for (int p = 0; p < 6; ++p) {
      int shift = shifts[p], nbits = bitsArr[p], nb = 1 << nbits;
      hist[tid] = 0;
      __syncthreads();
      for (int pos = msub; pos < mcnt; pos += 4) {
        unsigned long long key = mkeys[pos];
        if ((key >> (shift + nbits)) == pref)
          atomicAdd(&hist[(int)((key >> shift) & (nb - 1))], 1);
      }
      __syncthreads();
      if (tid < nb) sufs[tid] = hist[tid];
      __syncthreads();
      for (int off = 1; off < nb; off <<= 1) {
        int add = 0;
        if (tid < nb && tid + off < nb) add = sufs[tid + off];
        __syncthreads();
        if (tid < nb) sufs[tid] += add;
        __syncthreads();
      }
      if (tid < nb) {
        int sthis = sufs[tid];
        int snext = (tid + 1 < nb) ? sufs[tid + 1] : 0;
        if (sthis >= k && snext < k) { scal[0] = tid; scal[1] = k - snext; }
      }
      __syncthreads();
      pref = (pref << nbits) | (unsigned)scal[0];
      k = scal[1];
      __syncthreads();
    }
  }

  // ---- gather (keys unique -> exactly min(cnt,K1) survivors) ----
  if (tid == 0) scal[2] = 0;
  __syncthreads();
  for (int pos = msub; pos < mcnt; pos += 4) {
    unsigned long long key = mkeys[pos];
    if (key >= pref) {
      int p2 = atomicAdd(&scal[2], 1);
      if (p2 < 128) { sk[p2] = key; si[p2] = 16383 - (int)(key & 16383); }
    }
  }
  __syncthreads();
  int gcnt = scal[2];
  if (tid < K1 && tid >= gcnt) { sk[tid] = 0ull; si[tid] = 0; }  // weight-0 pads

  sort_desc(sk, si, K1, tid);

  if (which == 0) {
    if (tid < 32) {
      selIdx[outBase + tid] = si[tid];
      selW[outBase + tid]   = (sk[tid] != 0ull) ? 1.f : 0.f;
    }
    return;
  }

  // ---- stage 2: top-64 of 128 by (uncertainty desc, candidate pos asc) ----
  if (tid < 128) {
    cIdx[tid] = si[tid];
    cVal[tid] = (sk[tid] != 0ull) ? 1 : 0;
  }
  __syncthreads();
  if (tid < 128) {
    float u2 = cVal[tid] ? unc[(size_t)b*HW + cIdx[tid]] : NEGV;
    sk[tid] = ((unsigned long long)f2mono(u2) << 7) | (unsigned)(127 - tid);
    si[tid] = tid;
  }
  sort_desc(sk, si, 128, tid);
  if (tid < 64) {
    int t = si[tid];
    selIdx[outBase + tid] = cIdx[t];
    selW[outBase + tid]   = cVal[t] ? 1.f : 0.f;
  }
}

__global__ __launch_bounds__(256) void k_selc2(
    const int* __restrict__ bcnt, const unsigned long long* __restrict__ ckeys,
    const float* __restrict__ unc,
    int* __restrict__ selIdx, float* __restrict__ selW,
    int* __restrict__ cf, int* __restrict__ cb) {
  __shared__ __align__(16) char sh[4608];
  selc_body(bcnt, ckeys, unc, selIdx, selW, cf, cb, blockIdx.x, threadIdx.x, sh);
}

// ============ matmul body: EXACT round-3 structure (108 us, 72 VGPR, no spill) ============
// Do NOT register-pipeline (rounds 4/5 spilled both capped and uncapped).
// Do NOT run selc+mm8 sequentially in one block (round 9: VGPR 72->124, -29%).
#define BK 32
#define LDA 132

__device__ void mm8_body(
    const float* __restrict__ feat, const float* __restrict__ w1T,
    const int* __restrict__ mcls,
    float* __restrict__ chanSum, float* __restrict__ chanSq,
    float* __restrict__ rawout, int bid, int tid, float* smem) {
  float* As = smem;
  float* Bs = smem + BK*LDA;
  int ct = bid & 1;
  int rt = bid >> 1;
  int b  = rt >> 7;
  int i0 = (rt & 127) << 7;
  int c0 = ct << 7;
  int tx = tid & 15, ty = tid >> 4;
  float acc[8][8];
  #pragma unroll
  for (int r = 0; r < 8; ++r)
    #pragma unroll
    for (int c = 0; c < 8; ++c) acc[r][c] = 0.f;

  for (int kc = 0; kc < 8; ++kc) {
    int d0 = kc * BK;
    #pragma unroll
    for (int it = 0; it < 4; ++it) {
      int e = it*1024 + tid*4;
      int k = e >> 7, r = e & 127;
      float4 v = *(const float4*)&feat[((size_t)(b*DIM + d0 + k))*HW + i0 + r];
      *(float4*)&As[k*LDA + r] = v;
    }
    #pragma unroll
    for (int it = 0; it < 4; ++it) {
      int e = it*1024 + tid*4;
      int k = e >> 7, c = e & 127;
      float4 v = *(const float4*)&w1T[(size_t)(d0 + k)*DIM + c0 + c];
      *(float4*)&Bs[k*LDA + c] = v;
    }
    __syncthreads();
    #pragma unroll
    for (int k = 0; k < BK; ++k) {
      float4 a0 = *(const float4*)&As[k*LDA + ty*4];
      float4 a1 = *(const float4*)&As[k*LDA + 64 + ty*4];
      float4 b0 = *(const float4*)&Bs[k*LDA + tx*4];
      float4 b1 = *(const float4*)&Bs[k*LDA + 64 + tx*4];
      float ar[8] = {a0.x,a0.y,a0.z,a0.w, a1.x,a1.y,a1.z,a1.w};
      float bc[8] = {b0.x,b0.y,b0.z,b0.w, b1.x,b1.y,b1.z,b1.w};
      #pragma unroll
      for (int r = 0; r < 8; ++r)
        #pragma unroll
        for (int c = 0; c < 8; ++c)
          acc[r][c] += ar[r]*bc[c];
    }
    __syncthreads();
  }

  // ---- BN stats partials ----
  float* pS = smem;
  float* pQ = smem + 2048;
  #pragma unroll
  for (int c = 0; c < 8; ++c) {
    int lcol = (c < 4) ? (tx*4 + c) : (64 + tx*4 + (c - 4));
    float s = 0.f, q = 0.f;
    #pragma unroll
    for (int r = 0; r < 8; ++r) { float v = acc[r][c]; s += v; q += v*v; }
    pS[ty*128 + lcol] = s;
    pQ[ty*128 + lcol] = q;
  }
  __syncthreads();
  if (tid < 128) {
    float s = 0.f, q = 0.f;
    #pragma unroll
    for (int t2 = 0; t2 < 16; ++t2) { s += pS[t2*128 + tid]; q += pQ[t2*128 + tid]; }
    atomicAdd(&chanSum[c0 + tid], s);
    atomicAdd(&chanSq[c0 + tid],  q);
  }

  // ---- store raw rows for valid pixels ----
  #pragma unroll
  for (int r = 0; r < 8; ++r) {
    int lrow = (r < 4) ? (ty*4 + r) : (64 + ty*4 + (r - 4));
    int g = rt*128 + lrow;
    if (mcls[g] != 0) {
      float4 lo; lo.x = acc[r][0]; lo.y = acc[r][1]; lo.z = acc[r][2]; lo.w = acc[r][3];
      float4 hi; hi.x = acc[r][4]; hi.y = acc[r][5]; hi.z = acc[r][6]; hi.w = acc[r][7];
      *(float4*)&rawout[(size_t)g*DIM + c0 + tx*4]      = lo;
      *(float4*)&rawout[(size_t)g*DIM + c0 + 64 + tx*4] = hi;
    }
  }
}

// merged matmul + selection: selection blocks 0..nSel-1 issue FIRST so they
// overlap the matmul; exclusive branch (one body per block) keeps VGPR at 72.
// Both bodies share ONE 33,792 B LDS buffer.
__global__ __launch_bounds__(256) void k_mmsel(
    const float* __restrict__ feat, const float* __restrict__ w1T,
    const int* __restrict__ mcls,
    float* __restrict__ chanSum, float* __restrict__ chanSq,
    float* __restrict__ rawout,
    const int* __restrict__ bcnt, const unsigned long long* __restrict__ ckeys,
    const float* __restrict__ unc,
    int* __restrict__ selIdx, float* __restrict__ selW,
    int* __restrict__ cf, int* __restrict__ cb, int nSel) {
  __shared__ __align__(16) float smem[2*BK*LDA];
  int bid = blockIdx.x;
  if (bid < nSel)
    selc_body(bcnt, ckeys, unc, selIdx, selW, cf, cb, bid, threadIdx.x, (char*)smem);
  else
    mm8_body(feat, w1T, mcls, chanSum, chanSq, rawout, bid - nSel, threadIdx.x, smem);
}

// ============ fused post-matmul: bnsum (blocks 0..255) + rowproj x4 (256..575) ============
__global__ __launch_bounds__(256) void k_post(
    const float* __restrict__ raw, const int* __restrict__ mcls,
    const float* __restrict__ chanSum, const float* __restrict__ chanSq,
    const float* __restrict__ gamma, const float* __restrict__ beta,
    const float* __restrict__ w2, const float* __restrict__ b2,
    const int* __restrict__ selIdx, const float* __restrict__ selW,
    float* __restrict__ S1, float* __restrict__ S0,
    float* __restrict__ rows) {
  __shared__ __align__(16) float sh[2048];
  const float nconst = (float)(NBATCH * HW);
  int tid = threadIdx.x;

  if (blockIdx.x < 256) {
    float* p1 = sh;
    float* p2 = sh + 1024;
    int w = tid >> 6, lane = tid & 63;
    int p0 = blockIdx.x << 8;
    int b = p0 >> 14;
    int ch = lane*4;
    float4 G = *(const float4*)&gamma[ch];
    float4 Bt = *(const float4*)&beta[ch];
    float4 CS = *(const float4*)&chanSum[ch];
    float4 CQ = *(const float4*)&chanSq[ch];
    float m0 = CS.x/nconst, m1 = CS.y/nconst, m2 = CS.z/nconst, m3 = CS.w/nconst;
    float v0 = CQ.x/nconst - m0*m0, v1 = CQ.y/nconst - m1*m1;
    float v2 = CQ.z/nconst - m2*m2, v3 = CQ.w/nconst - m3*m3;
    float i0 = 1.0f/sqrtf(v0 + 1e-5f), i1 = 1.0f/sqrtf(v1 + 1e-5f);
    float i2 = 1.0f/sqrtf(v2 + 1e-5f), i3 = 1.0f/sqrtf(v3 + 1e-5f);
    float A0 = G.x*i0, A1 = G.y*i1, A2 = G.z*i2, A3 = G.w*i3;
    float s1[4] = {0,0,0,0}, s0[4] = {0,0,0,0};
    int g0 = p0 + w*64;
    for (int t = 0; t < 64; ++t) {
      int g = g0 + t;
      int cls = mcls[g];
      if (cls == 0) continue;
      float4 v = *(const float4*)&raw[(size_t)g*DIM + ch];
      float r0 = A0*(v.x - m0) + Bt.x; r0 = r0 > 0.f ? r0 : 0.f;
      float r1 = A1*(v.y - m1) + Bt.y; r1 = r1 > 0.f ? r1 : 0.f;
      float r2 = A2*(v.z - m2) + Bt.z; r2 = r2 > 0.f ? r2 : 0.f;
      float r3 = A3*(v.w - m3) + Bt.w; r3 = r3 > 0.f ? r3 : 0.f;
      if (cls == 1) { s1[0]+=r0; s1[1]+=r1; s1[2]+=r2; s1[3]+=r3; }
      else          { s0[0]+=r0; s0[1]+=r1; s0[2]+=r2; s0[3]+=r3; }
    }
    #pragma unroll
    for (int j = 0; j < 4; ++j) {
      p1[w*256 + ch + j] = s1[j];
      p2[w*256 + ch + j] = s0[j];
    }
    __syncthreads();
    float a = p1[tid] + p1[256+tid] + p1[512+tid] + p1[768+tid];
    float d = p2[tid] + p2[256+tid] + p2[512+tid] + p2[768+tid];
    atomicAdd(&S1[b*DIM + tid], a);
    atomicAdd(&S0[b*DIM + tid], d);
  } else {
    float* rl  = sh;
    float* red = sh + 1024;
    int blk = blockIdx.x - 256;
    int slot0 = blk * 4;
    int pair = slot0 / NPP;
    int b = pair >> 1;
    int e = tid;
    float m = chanSum[e] / nconst;
    float v = chanSq[e] / nconst - m*m;
    float istd = 1.0f / sqrtf(v + 1e-5f);
    float A = gamma[e]*istd;
    float Bt = beta[e];
    bool ok[4];
    #pragma unroll
    for (int s = 0; s < 4; ++s) {
      int slot = slot0 + s;
      ok[s] = (selW[slot] != 0.f);
      float rv = 0.f;
      if (ok[s]) {
        int i = selIdx[slot];
        float acc = raw[((size_t)b*HW + i)*DIM + e];
        float bn = A*(acc - m) + Bt;
        rv = bn > 0.f ? bn : 0.f;
      }
      rl[s*256 + e] = rv;
    }
    __syncthreads();
    float b2e = b2[e];
    float pj[4] = {b2e, b2e, b2e, b2e};
    const float4* w4 = (const float4*)&w2[(size_t)e*DIM];
    #pragma unroll 8
    for (int d4 = 0; d4 < DIM/4; ++d4) {
      float4 w = w4[d4];
      #pragma unroll
      for (int s = 0; s < 4; ++s) {
        float4 a = *(const float4*)&rl[s*256 + d4*4];
        pj[s] += a.x*w.x + a.y*w.y + a.z*w.z + a.w*w.w;
      }
    }
    #pragma unroll
    for (int s = 0; s < 4; ++s) red[s*256 + e] = pj[s]*pj[s];
    __syncthreads();
    for (int off = 128; off > 0; off >>= 1) {
      if (e < off) {
        #pragma unroll
        for (int s = 0; s < 4; ++s) red[s*256 + e] += red[s*256 + e + off];
      }
      __syncthreads();
    }
    #pragma unroll
    for (int s = 0; s < 4; ++s) {
      float sc = 1.f / fmaxf(sqrtf(red[s*256]), 1e-12f);
      rows[(size_t)(slot0 + s)*DIM + e] = ok[s] ? pj[s]*sc : 0.f;
    }
  }
}

// ============ pair-loss body ============
__device__ void pair_body(
    const float* __restrict__ rows, const float* __restrict__ selW,
    const int* __restrict__ cf, const int* __restrict__ cb,
    float* __restrict__ BL, float* __restrict__ INCF, int pair, int tid) {
  __shared__ float q[32*257];
  __shared__ float pacc[256], nacc[256];
  __shared__ float red[64];
  int b = pair >> 1, c = pair & 1;
  for (int l = tid; l < 32*DIM; l += 256) {
    int r = l >> 8, d = l & 255;
    q[r*257 + d] = rows[((size_t)pair*NPP + r)*DIM + d];
  }
  __syncthreads();
  int g = tid >> 5, r = tid & 31;
  float ap = 0.f, an = 0.f;
  for (int so = 0; so < 8; ++so) {
    int s = so*8 + g;
    const float* Pr = &rows[((size_t)pair*NPP + 32 + s)*DIM];
    const float* Nr = &rows[((size_t)pair*NPP + 96 + s)*DIM];
    float dp = 0.f, dn = 0.f;
    for (int d = 0; d < DIM; ++d) {
      float qv = q[r*257 + d];
      dp += Pr[d]*qv;
      dn += Nr[d]*qv;
    }
    ap += expf(dp*10.f) * selW[pair*NPP + 32 + s];
    an += expf(dn*10.f) * selW[pair*NPP + 96 + s];
  }
  pacc[tid] = ap; nacc[tid] = an;
  __syncthreads();
  if (tid < 32) {
    float p = 0.f, n = 0.f;
    for (int gg = 0; gg < 8; ++gg) { p += pacc[gg*32 + tid]; n += nacc[gg*32 + tid]; }
    int amC = (c == 0) ? cf[b] : cb[b];
    int nmC = (c == 0) ? cb[b] : cf[b];
    bool inc = (amC >= 1) && (nmC >= 1);
    if (!inc) p += 1.f;
    float per = -logf(p / (p + n + 1e-8f));
    float af = selW[pair*NPP + tid];
    red[tid]      = per*af;
    red[32 + tid] = af;
  }
  __syncthreads();
  if (tid == 0) {
    float s = 0.f, sa = 0.f;
    for (int rr = 0; rr < 32; ++rr) { s += red[rr]; sa += red[32+rr]; }
    int amC = (c == 0) ? cf[b] : cb[b];
    int nmC = (c == 0) ? cb[b] : cf[b];
    bool inc = (amC >= 1) && (nmC >= 1);
    float bl = s / fmaxf(sa, 1.f);
    BL[pair]   = inc ? bl : 0.f;
    INCF[pair] = inc ? 1.f : 0.f;
  }
}

// ============ prototype body (64 threads) ============
__device__ void proto_body(
    const float* __restrict__ S1, const float* __restrict__ S0,
    const int* __restrict__ cf, const int* __restrict__ cb,
    const float* __restrict__ w2, const float* __restrict__ b2,
    float* __restrict__ qbuf, int idx, int l) {
  int b = idx >> 1, side = idx & 1;
  const float* S = (side == 0) ? &S1[b*DIM] : &S0[b*DIM];
  float cnt = (float)((side == 0) ? cf[b] : cb[b]);
  float m[4]; float n2p = 0.f;
  #pragma unroll
  for (int k = 0; k < 4; ++k) {
    int e = l + 64*k;
    float acc = 0.f;
    const float* w2r = &w2[(size_t)e*DIM];
    for (int d = 0; d < DIM; ++d) acc += S[d]*w2r[d];
    float mv = (acc + cnt*b2[e]) / fmaxf(cnt, 1.f);
    m[k] = mv; n2p += mv*mv;
  }
  #pragma unroll
  for (int off = 32; off > 0; off >>= 1) n2p += __shfl_down(n2p, off, 64);
  float n2 = __shfl(n2p, 0, 64);
  float sc = 1.f / fmaxf(sqrtf(n2), 1e-12f);
  #pragma unroll
  for (int k = 0; k < 4; ++k)
    qbuf[(size_t)(side*4 + b)*DIM + l + 64*k] = m[k]*sc;
}

// ============ global-loss body (one wave) ============
__device__ void glob_body(
    const float* __restrict__ qbuf,
    const int* __restrict__ cf, const int* __restrict__ cb,
    const float* __restrict__ BL, const float* __restrict__ INCF,
    float* __restrict__ out, int l) {
  float qf[4][4], qb[4][4];
  #pragma unroll
  for (int b = 0; b < 4; ++b)
    #pragma unroll
    for (int k = 0; k < 4; ++k) {
      qf[b][k] = qbuf[(size_t)b*DIM + l + 64*k];
      qb[b][k] = qbuf[(size_t)(4 + b)*DIM + l + 64*k];
    }
  float pd[24];
  #pragma unroll
  for (int j = 0; j < 4; ++j)
    #pragma unroll
    for (int b = 0; b < 4; ++b) {
      float s = 0.f;
      #pragma unroll
      for (int k = 0; k < 4; ++k) s += qb[j][k]*qf[b][k];
      pd[j*4 + b] = s;
    }
  #pragma unroll
  for (int b = 0; b < 4; ++b) {
    float s1 = 0.f, s2 = 0.f;
    #pragma unroll
    for (int k = 0; k < 4; ++k) { s1 += qf[b][k]*qf[b][k]; s2 += qb[b][k]*qb[b][k]; }
    pd[16 + b] = s1; pd[20 + b] = s2;
  }
  #pragma unroll
  for (int t = 0; t < 24; ++t)
    #pragma unroll
    for (int off = 32; off > 0; off >>= 1)
      pd[t] += __shfl_down(pd[t], off, 64);
  if (l == 0) {
    bool vg[4]; float vgs = 0.f;
    for (int b = 0; b < 4; ++b) {
      vg[b] = (cf[b] >= 1) && (cb[b] >= 1);
      if (vg[b]) vgs += 1.f;
    }
    float gsum = 0.f;
    for (int b = 0; b < 4; ++b) {
      float nf = 0.f, nb = 0.f;
      for (int j = 0; j <= b; ++j) if (vg[j]) {
        nf += expf(10.f*pd[j*4 + b]);
        nb += expf(10.f*pd[b*4 + j]);
      }
      float pf = expf(10.f*pd[16 + b]);
      float pb = expf(10.f*pd[20 + b]);
      float lg = -logf(pf/(pf + nf + 1e-8f)) - logf(pb/(pb + nb + 1e-8f));
      if (vg[b]) gsum += lg;
    }
    float l_global = gsum / fmaxf(vgs, 1.f);
    float bls = 0.f, incs = 0.f;
    for (int p = 0; p < 8; ++p) { bls += BL[p]; incs += INCF[p]; }
    float l_local = bls / fmaxf(incs, 1.f);
    out[0] = l_local + 0.5f*l_global;
    out[1] = l_local;
    out[2] = l_global;
  }
}

// merged pair (blocks 0..7) + proto (blocks 8..15) + last-block global loss.
__global__ __launch_bounds__(256) void k_pp(
    const float* __restrict__ rows, const float* __restrict__ selW,
    const int* __restrict__ cf, const int* __restrict__ cb,
    float* __restrict__ BL, float* __restrict__ INCF,
    const float* __restrict__ S1, const float* __restrict__ S0,
    const float* __restrict__ w2, const float* __restrict__ b2,
    float* __restrict__ qbuf, int* __restrict__ ppcnt,
    float* __restrict__ out) {
  __shared__ int isLast;
  if (blockIdx.x < 8) {
    pair_body(rows, selW, cf, cb, BL, INCF, blockIdx.x, threadIdx.x);
  } else {
    if (threadIdx.x < 64)
      proto_body(S1, S0, cf, cb, w2, b2, qbuf, blockIdx.x - 8, threadIdx.x);
  }
  __syncthreads();
  __threadfence();                     // make this block's writes device-visible
  if (threadIdx.x == 0) isLast = (atomicAdd(ppcnt, 1) == 15);
  __syncthreads();
  if (isLast) {
    __threadfence();                   // acquire side
    if (threadIdx.x < 64)
      glob_body(qbuf, cf, cb, BL, INCF, out, threadIdx.x);
  }
}

// ================== fallback path (small workspace) ==================
__global__ void k_mask(const float* __restrict__ po, const float* __restrict__ pa,
                       const float* __restrict__ unc, const int* __restrict__ lab,
                       int* __restrict__ mcls, int* __restrict__ cf, int* __restrict__ cb) {
  int g = blockIdx.x * 256 + threadIdx.x;
  int b = g >> 14;
  int i = g & (HW - 1);
  float o0 = po[(size_t)(b*2+0)*HW + i];
  float o1 = po[(size_t)(b*2+1)*HW + i];
  float a0 = pa[(size_t)(b*2+0)*HW + i];
  float a1 = pa[(size_t)(b*2+1)*HW + i];
  bool rel = ((o1 > o0) == (a1 > a0));
  bool valid = rel && (unc[g] > 0.5f);
  int l = lab[g];
  int cls = valid ? ((l == 1) ? 1 : 2) : 0;
  mcls[g] = cls;
  if (cls == 1) atomicAdd(&cf[b], 1);
  if (cls == 2) atomicAdd(&cb[b], 1);
}

template<int MODE>
__global__ __launch_bounds__(256) void k_matmul(
    const float* __restrict__ feat, const float* __restrict__ w1,
    float* __restrict__ chanSum, float* __restrict__ chanSq,
    const float* __restrict__ meanr, const float* __restrict__ istd,
    const float* __restrict__ gamma, const float* __restrict__ beta,
    const int* __restrict__ mcls,
    float* __restrict__ S1, float* __restrict__ S0) {
  __shared__ __align__(16) float As[64*68];
  __shared__ __align__(16) float Bs[64*68];
  __shared__ float cA[64], cB[64];
  int tid = threadIdx.x;
  int rt = blockIdx.x;
  int ct = blockIdx.y;
  int b  = rt >> 8;
  int i0 = (rt & 255) << 6;
  int c0 = ct << 6;
  int tx = tid & 15, ty = tid >> 4;
  float acc[4][4] = {{0.f,0.f,0.f,0.f},{0.f,0.f,0.f,0.f},{0.f,0.f,0.f,0.f},{0.f,0.f,0.f,0.f}};
  for (int kc = 0; kc < 4; ++kc) {
    int d0 = kc << 6;
    #pragma unroll
    for (int it = 0; it < 4; ++it) {
      int k  = it*16 + (tid >> 4);
      int rq = tid & 15;
      float4 v = *(const float4*)&feat[((size_t)(b*DIM + d0 + k))*HW + i0 + rq*4];
      *(float4*)&As[k*68 + rq*4] = v;
    }
    #pragma unroll
    for (int it = 0; it < 4; ++it) {
      int col = it*16 + (tid >> 4);
      int kq  = tid & 15;
      float4 v = *(const float4*)&w1[(size_t)(c0 + col)*DIM + d0 + kq*4];
      Bs[(kq*4+0)*68 + col] = v.x;
      Bs[(kq*4+1)*68 + col] = v.y;
      Bs[(kq*4+2)*68 + col] = v.z;
      Bs[(kq*4+3)*68 + col] = v.w;
    }
    __syncthreads();
    #pragma unroll
    for (int k = 0; k < 64; ++k) {
      float4 av = *(const float4*)&As[k*68 + ty*4];
      float4 bv = *(const float4*)&Bs[k*68 + tx*4];
      float aa[4] = {av.x, av.y, av.z, av.w};
      float bb[4] = {bv.x, bv.y, bv.z, bv.w};
      #pragma unroll
      for (int rr = 0; rr < 4; ++rr)
        #pragma unroll
        for (int cc = 0; cc < 4; ++cc)
          acc[rr][cc] += aa[rr]*bb[cc];
    }
    __syncthreads();
  }
  if (tid < 64) { cA[tid] = 0.f; cB[tid] = 0.f; }
  __syncthreads();
  if (MODE == 0) {
    float s[4] = {0,0,0,0}, q[4] = {0,0,0,0};
    #pragma unroll
    for (int rr = 0; rr < 4; ++rr)
      #pragma unroll
      for (int cc = 0; cc < 4; ++cc) { float v = acc[rr][cc]; s[cc] += v; q[cc] += v*v; }
    #pragma unroll
    for (int cc = 0; cc < 4; ++cc) {
      atomicAdd(&cA[tx*4+cc], s[cc]);
      atomicAdd(&cB[tx*4+cc], q[cc]);
    }
    __syncthreads();
    if (tid < 64) {
      atomicAdd(&chanSum[c0 + tid], cA[tid]);
      atomicAdd(&chanSq[c0 + tid],  cB[tid]);
    }
  } else {
    float A[4], M[4], Bt[4];
    #pragma unroll
    for (int cc = 0; cc < 4; ++cc) {
      int c = c0 + tx*4 + cc;
      A[cc] = gamma[c]*istd[c]; M[cc] = meanr[c]; Bt[cc] = beta[c];
    }
    float s1[4] = {0,0,0,0}, s0[4] = {0,0,0,0};
    #pragma unroll
    for (int rr = 0; rr < 4; ++rr) {
      int g = rt*64 + ty*4 + rr;
      int cls = mcls[g];
      if (cls == 0) continue;
      #pragma unroll
      for (int cc = 0; cc < 4; ++cc) {
        float v = A[cc]*(acc[rr][cc] - M[cc]) + Bt[cc];
        v = v > 0.f ? v : 0.f;
        if (cls == 1) s1[cc] += v; else s0[cc] += v;
      }
    }
    #pragma unroll
    for (int cc = 0; cc < 4; ++cc) {
      atomicAdd(&cA[tx*4+cc], s1[cc]);
      atomicAdd(&cB[tx*4+cc], s0[cc]);
    }
    __syncthreads();
    if (tid < 64) {
      atomicAdd(&S1[b*DIM + c0 + tid], cA[tid]);
      atomicAdd(&S0[b*DIM + c0 + tid], cB[tid]);
    }
  }
}

__global__ void k_stats(const float* __restrict__ chanSum, const float* __restrict__ chanSq,
                        float* __restrict__ meanr, float* __restrict__ istd) {
  int e = threadIdx.x;
  const float n = (float)(NBATCH * HW);
  float m = chanSum[e] / n;
  float v = chanSq[e] / n - m*m;
  meanr[e] = m;
  istd[e]  = 1.0f / sqrtf(v + 1e-5f);
}

__global__ __launch_bounds__(256) void k_select(
    const int* __restrict__ mcls,
    const float* __restrict__ r_anc, const float* __restrict__ r_pos, const float* __restrict__ r_neg,
    const float* __restrict__ unc,
    int* __restrict__ selIdx, float* __restrict__ selW) {
  __shared__ int hist[256];
  __shared__ int sufs[256];
  __shared__ unsigned long long sk[128];
  __shared__ int si[128];
  __shared__ int cIdx[128];
  __shared__ unsigned char cVal[128];
  __shared__ int sh_bin, sh_k, gcnt;

  int tid  = threadIdx.x;
  int task = blockIdx.x;
  int pair = task / 3, which = task % 3;
  int b = pair >> 1, c = pair & 1;
  int wantA = (c == 0) ? 1 : 2;
  int want  = (which == 2) ? (3 - wantA) : wantA;
  const int* mc = mcls + (size_t)b * HW;
  const float* r = (which == 0) ? r_anc : (which == 1 ? r_pos : r_neg);
  r += (size_t)(b*2 + c) * HW;

  int K1 = (which == 0) ? 32 : 128;
  int outBase = pair*NPP + (which == 0 ? 0 : (which == 1 ? 32 : 96));

  const int shifts[6]  = {38, 30, 22, 14, 6, 0};
  const int bitsArr[6] = { 8,  8,  8,  8, 8, 6};
  unsigned long long pref = 0;
  int k = K1;
  for (int p = 0; p < 6; ++p) {
    int shift = shifts[p];
    int nbits = bitsArr[p];
    int nb = 1 << nbits;
    hist[tid] = 0;
    __syncthreads();
    int lastBin = -1, lc = 0;
    #pragma unroll 4
    for (int j = 0; j < 64; ++j) {
      int i = tid + j*256;
      float kv = (mc[i] == want) ? r[i] : NEGV;
      unsigned long long key = ((unsigned long long)f2mono(kv) << 14) | (unsigned)(16383 - i);
      if ((key >> (shift + nbits)) == pref) {
        int bin = (int)((key >> shift) & (nb - 1));
        if (bin == lastBin) { ++lc; }
        else {
          if (lastBin >= 0) atomicAdd(&hist[lastBin], lc);
          lastBin = bin; lc = 1;
        }
      }
    }
    if (lastBin >= 0) atomicAdd(&hist[lastBin], lc);
    __syncthreads();
    if (tid < nb) sufs[tid] = hist[tid];
    __syncthreads();
    for (int off = 1; off < nb; off <<= 1) {
      int add = 0;
      if (tid < nb && tid + off < nb) add = sufs[tid + off];
      __syncthreads();
      if (tid < nb) sufs[tid] += add;
      __syncthreads();
    }
    if (tid < nb) {
      int sthis = sufs[tid];
      int snext = (tid + 1 < nb) ? sufs[tid + 1] : 0;
      if (sthis >= k && snext < k) { sh_bin = tid; sh_k = k - snext; }
    }
    __syncthreads();
    pref = (pref << nbits) | (unsigned)sh_bin;
    k = sh_k;
    __syncthreads();
  }

  if (tid == 0) gcnt = 0;
  __syncthreads();
  #pragma unroll 4
  for (int j = 0; j < 64; ++j) {
    int i = tid + j*256;
    float kv = (mc[i] == want) ? r[i] : NEGV;
    unsigned long long key = ((unsigned long long)f2mono(kv) << 14) | (unsigned)(16383 - i);
    if (key >= pref) {
      int p2 = atomicAdd(&gcnt, 1);
      if (p2 < 128) { sk[p2] = key; si[p2] = i; }
    }
  }
  __syncthreads();
  if (tid < K1 && tid >= gcnt) { sk[tid] = 0ull; si[tid] = 0; }

  sort_desc(sk, si, K1, tid);

  if (which == 0) {
    if (tid < 32) {
      selIdx[outBase + tid] = si[tid];
      selW[outBase + tid]   = ((sk[tid] >> 14) >= 0x80000000ull) ? 1.f : 0.f;
    }
    return;
  }

  if (tid < 128) {
    cIdx[tid] = si[tid];
    cVal[tid] = ((sk[tid] >> 14) >= 0x80000000ull) ? 1 : 0;
  }
  __syncthreads();
  if (tid < 128) {
    float u2 = cVal[tid] ? unc[(size_t)b*HW + cIdx[tid]] : NEGV;
    sk[tid] = ((unsigned long long)f2mono(u2) << 7) | (unsigned)(127 - tid);
    si[tid] = tid;
  }
  sort_desc(sk, si, 128, tid);
  if (tid < 64) {
    int t = si[tid];
    selIdx[outBase + tid] = cIdx[t];
    selW[outBase + tid]   = cVal[t] ? 1.f : 0.f;
  }
}

__global__ __launch_bounds__(256) void k_rowproj(
    const float* __restrict__ feat, const float* __restrict__ w1, const float* __restrict__ w2,
    const float* __restrict__ b2, const float* __restrict__ gamma, const float* __restrict__ beta,
    const float* __restrict__ meanr, const float* __restrict__ istd,
    const int* __restrict__ selIdx, float* __restrict__ rows) {
  __shared__ __align__(16) float fr[DIM];
  __shared__ __align__(16) float rl[DIM];
  __shared__ float red[256];
  int slot = blockIdx.x;
  int pair = slot / NPP;
  int b = pair >> 1;
  int i = selIdx[slot];
  int e = threadIdx.x;
  fr[e] = feat[((size_t)(b*DIM + e))*HW + i];
  __syncthreads();
  float acc = 0.f;
  {
    const float4* f4 = (const float4*)fr;
    const float4* w4 = (const float4*)&w1[(size_t)e*DIM];
    #pragma unroll 8
    for (int d = 0; d < DIM/4; ++d) {
      float4 a = f4[d], w = w4[d];
      acc += a.x*w.x + a.y*w.y + a.z*w.z + a.w*w.w;
    }
  }
  float bn = gamma[e]*istd[e]*(acc - meanr[e]) + beta[e];
  rl[e] = bn > 0.f ? bn : 0.f;
  __syncthreads();
  float pj = b2[e];
  {
    const float4* f4 = (const float4*)rl;
    const float4* w4 = (const float4*)&w2[(size_t)e*DIM];
    #pragma unroll 8
    for (int d = 0; d < DIM/4; ++d) {
      float4 a = f4[d], w = w4[d];
      pj += a.x*w.x + a.y*w.y + a.z*w.z + a.w*w.w;
    }
  }
  red[e] = pj*pj;
  __syncthreads();
  for (int off = 128; off > 0; off >>= 1) {
    if (e < off) red[e] += red[e+off];
    __syncthreads();
  }
  float sc = 1.f / fmaxf(sqrtf(red[0]), 1e-12f);
  rows[(size_t)slot*DIM + e] = pj * sc;
}

__global__ __launch_bounds__(256) void k_pair(
    const float* __restrict__ rows, const float* __restrict__ selW,
    const int* __restrict__ cf, const int* __restrict__ cb,
    float* __restrict__ BL, float* __restrict__ INCF) {
  pair_body(rows, selW, cf, cb, BL, INCF, blockIdx.x, threadIdx.x);
}

__global__ __launch_bounds__(64) void k_proto(
    const float* __restrict__ S1, const float* __restrict__ S0,
    const int* __restrict__ cf, const int* __restrict__ cb,
    const float* __restrict__ w2, const float* __restrict__ b2,
    float* __restrict__ qbuf) {
  proto_body(S1, S0, cf, cb, w2, b2, qbuf, blockIdx.x, threadIdx.x);
}

__global__ __launch_bounds__(64) void k_glob(
    const float* __restrict__ qbuf,
    const int* __restrict__ cf, const int* __restrict__ cb,
    const float* __restrict__ BL, const float* __restrict__ INCF,
    float* __restrict__ out) {
  glob_body(qbuf, cf, cb, BL, INCF, out, threadIdx.x);
}

extern "C" void kernel_launch(void* const* d_in, const int* in_sizes, int n_in,
                              void* d_out, int out_size, void* d_ws, size_t ws_size,
                              hipStream_t stream) {
  const float* feat     = (const float*)d_in[0];
  const int*   labels   = (const int*)  d_in[1];
  const float* prob_ori = (const float*)d_in[2];
  const float* prob_aug = (const float*)d_in[3];
  const float* unc      = (const float*)d_in[4];
  const float* r_anc    = (const float*)d_in[5];
  const float* r_pos    = (const float*)d_in[6];
  const float* r_neg    = (const float*)d_in[7];
  const float* w1       = (const float*)d_in[8];
  // d_in[9] = b1: cancels inside BN (mean subtraction), unused
  const float* gamma    = (const float*)d_in[10];
  const float* beta     = (const float*)d_in[11];
  const float* w2       = (const float*)d_in[12];
  const float* b2       = (const float*)d_in[13];

  char* ws = (char*)d_ws;
  float* chanSum = (float*)(ws + OFF_CHAN_SUM);
  float* chanSq  = (float*)(ws + OFF_CHAN_SQ);
  float* meanr   = (float*)(ws + OFF_MEAN);
  float* istd    = (float*)(ws + OFF_ISTD);
  float* S1      = (float*)(ws + OFF_S1);
  float* S0      = (float*)(ws + OFF_S0);
  int*   cf      = (int*)  (ws + OFF_CF);
  int*   cb      = (int*)  (ws + OFF_CB);
  float* BLp     = (float*)(ws + OFF_BL);
  float* INCp    = (float*)(ws + OFF_INCF);
  int*   ppcnt   = (int*)  (ws + OFF_PPCNT);
  float* qbuf    = (float*)(ws + OFF_QBUF);
  int*   bcnt    = (int*)  (ws + OFF_BCNT);
  int*   mclsp   = (int*)  (ws + OFF_MCLS);
  int*   selIdx  = (int*)  (ws + OFF_SELIDX);
  float* selW    = (float*)(ws + OFF_SELW);
  float* rowsbuf = (float*)(ws + OFF_ROWS);
  float* w1T     = (float*)(ws + OFF_W1T);
  float* rawbuf  = (float*)(ws + OFF_RAW);

  if (ws_size >= WS_NEED_FAST) {
    bool xl = (ws_size >= WS_NEED_XL);
    unsigned long long* ckeys = (unsigned long long*)(ws + (xl ? OFF_CKEYS_XL : OFF_RAW));

    k_maskc2<<<256, 256, 0, stream>>>(prob_ori, prob_aug, unc, labels,
                                      r_anc, r_pos, r_neg, w1,
                                      mclsp, bcnt, ckeys, w1T,
                                      chanSum, chanSq, S1, S0, ppcnt);
    if (xl) {
      // selection blocks FIRST (they now finish in ~10us, freeing their
      // residency slots for the 24 trailing matmul tiles almost immediately)
      k_mmsel<<<1024 + NSEL, 256, 0, stream>>>(feat, w1T, mclsp, chanSum, chanSq, rawbuf,
                                               bcnt, ckeys, unc, selIdx, selW, cf, cb, NSEL);
    } else {
      // ckeys aliases RAW: selection must finish before matmul writes raw
      k_selc2<<<24, 256, 0, stream>>>(bcnt, ckeys, unc, selIdx, selW, cf, cb);
      k_mmsel<<<1024, 256, 0, stream>>>(feat, w1T, mclsp, chanSum, chanSq, rawbuf,
                                        bcnt, ckeys, unc, selIdx, selW, cf, cb, 0);
    }

    k_post<<<576, 256, 0, stream>>>(rawbuf, mclsp, chanSum, chanSq, gamma, beta,
                                    w2, b2, selIdx, selW, S1, S0, rowsbuf);

    k_pp<<<16, 256, 0, stream>>>(rowsbuf, selW, cf, cb, BLp, INCp,
                                 S1, S0, w2, b2, qbuf, ppcnt, (float*)d_out);
  } else {
    // fallback: two-pass tiled matmul + direct selection
    hipMemsetAsync(d_ws, 0, 16384, stream);
    k_mask<<<256, 256, 0, stream>>>(prob_ori, prob_aug, unc, labels, mclsp, cf, cb);
    dim3 gmm(1024, 4);
    k_matmul<0><<<gmm, 256, 0, stream>>>(feat, w1, chanSum, chanSq,
                                         meanr, istd, gamma, beta, mclsp, S1, S0);
    k_stats<<<1, 256, 0, stream>>>(chanSum, chanSq, meanr, istd);
    k_matmul<1><<<gmm, 256, 0, stream>>>(feat, w1, chanSum, chanSq,
                                         meanr, istd, gamma, beta, mclsp, S1, S0);
    k_select<<<24, 256, 0, stream>>>(mclsp, r_anc, r_pos, r_neg, unc, selIdx, selW);
    k_rowproj<<<1280, 256, 0, stream>>>(feat, w1, w2, b2, gamma, beta, meanr, istd,
                                        selIdx, rowsbuf);
    k_pair<<<8, 256, 0, stream>>>(rowsbuf, selW, cf, cb, BLp, INCp);
    k_proto<<<8, 64, 0, stream>>>(S1, S0, cf, cb, w2, b2, qbuf);
    k_glob<<<1, 64, 0, stream>>>(qbuf, cf, cb, BLp, INCp, (float*)d_out);
  }
}